// Round 12
// baseline (910.651 us; speedup 1.0000x reference)
//
#include <hip/hip_runtime.h>
#include <cstdint>
#include <cstddef>

// ---- problem constants ----
#define N_    16
#define C_    16
#define T_    300
#define V_    25
#define D_    400
#define H_    2
#define DH_   200
#define FF_   1600
#define L_    9
#define W_    291
#define NW_   (N_*W_)      // 4656
#define NT_   (N_*T_)      // 4800
#define CW_   1552         // windows per chunk -> 3 chunks
#define RC_   (CW_*L_)     // 13968 rows per chunk (= 4*3492)
#define RCP_  14080        // padded chunk rows (110*128)

#define KP_   416          // K-pad of D (mult of 32), zero-filled in weights
#define SD_   512          // row stride of D-wide intermediates
#define SQKV_ 1280         // qkv row stride / QKV N-pad
#define SFF_  1664         // ffc row stride / FFN1 N-pad

// ---- workspace layout (bytes), total 119,803,904 ----
#define WIN_OFF   0u
#define WOUT_OFF  1064960u
#define W1_OFF    1490944u
#define W2_OFF    2875392u
#define XS_OFF    4579328u
#define QKV_OFF   9560064u
#define ACC_OFF   22011904u
#define OC_OFF    29691904u
#define YC_OFF    44109824u
#define HC_OFF    58527744u
#define FFC_OFF   72945664u

// s_waitcnt immediates (gfx9): vmcnt[3:0] | expcnt<<4 | lgkmcnt<<8 | vmcnt[5:4]<<14
#define WAIT_VM4   0xF74    // vmcnt<=4, lgkm/exp don't-care
#define WAIT_VM0   0xF70    // vmcnt<=0

using u16 = unsigned short;
using u32 = unsigned int;
using frag  = __attribute__((ext_vector_type(8))) short;   // 8 bf16
using f32x4 = __attribute__((ext_vector_type(4))) float;

__device__ __forceinline__ float bf2f(u16 u){
  return __uint_as_float(((u32)u) << 16);
}
// round-half-up bf16 (differs from RNE only on exact ties; 2 VALU)
__device__ __forceinline__ u16 f2bf(float f){
  return (u16)((__float_as_uint(f) + 0x8000u) >> 16);
}
// tanh-form gelu (max dev from erf-gelu ~1e-3; invisible at bf16)
__device__ __forceinline__ float gelu_f(float v){
  float v3  = v * v * v;
  float x2  = 1.5957691216f * v + 0.0713548162726f * v3;   // 2*0.7978845608*(v+0.044715 v^3)
  float e   = __expf(x2);
  float th  = 1.f - 2.f / (e + 1.f);                       // tanh(x2/2*2)=tanh(arg)
  return 0.5f * v * (1.f + th);
}
__device__ __forceinline__ void unpack8(uint4 v, float* o){
  o[0] = bf2f((u16)(v.x & 0xffffu)); o[1] = bf2f((u16)(v.x >> 16));
  o[2] = bf2f((u16)(v.y & 0xffffu)); o[3] = bf2f((u16)(v.y >> 16));
  o[4] = bf2f((u16)(v.z & 0xffffu)); o[5] = bf2f((u16)(v.z >> 16));
  o[6] = bf2f((u16)(v.w & 0xffffu)); o[7] = bf2f((u16)(v.w >> 16));
}

__global__ __launch_bounds__(256) void zero_kernel(float* __restrict__ acc, int n){
  int idx = blockIdx.x * 256 + threadIdx.x;
  if (idx < n) acc[idx] = 0.f;
}

// fp32 [sN,sK] -> bf16 [dN,dK], zero-filled pad
__global__ __launch_bounds__(256) void convw_kernel(const float* __restrict__ src,
                                                    u16* __restrict__ dst,
                                                    int dN, int dK, int sN, int sK){
  int idx = blockIdx.x * 256 + threadIdx.x;
  if (idx >= dN * dK) return;
  int n = idx / dK, k = idx % dK;
  dst[idx] = (n < sN && k < sK) ? f2bf(src[(size_t)n * sK + k]) : (u16)0;
}

// ---- xs[nt, d] (stride SD_) = x[n, d&15, t, d>>4] + pe[t,d] ----
__global__ __launch_bounds__(256) void embed_kernel(const float* __restrict__ x,
                                                    const float* __restrict__ pe,
                                                    u16* __restrict__ xs){
  int idx = blockIdx.x * 256 + threadIdx.x;
  if (idx >= NT_ * D_) return;
  int d  = idx % D_;
  int nt = idx / D_;
  int t  = nt % T_;
  int n  = nt / T_;
  float val = x[(((size_t)(n*C_ + (d & 15)))*T_ + t)*V_ + (d >> 4)] + pe[t*D_ + d];
  xs[(size_t)nt * SD_ + d] = f2bf(val);
}

// ---- MFMA GEMM: shared 128x128 tile, 3-deep LDS pipeline, cooperative
//      global_load_lds staging, raw s_barrier + vmcnt(4) (never 0).
//      Epilogue via stride-72 LDS tiles -> coalesced dwordx4 stores. ----
template<int ACT>
__global__ __launch_bounds__(256) void gemm_mfma(const u16* __restrict__ A, int lda,
                                                 const u16* __restrict__ B, int ldb,
                                                 const float* __restrict__ bias,
                                                 u16* __restrict__ C, int ldc,
                                                 int Nn, int KPd,
                                                 int gx, int gy){
  __shared__ u16 smem[24576];              // 48KB
  int id = blockIdx.x;
  int c  = id & 7, t = id >> 3;
  int bx = t % gx;
  int by = (t / gx) * 8 + c;               // XCD c owns M-tile residue class
  if (by >= gy) return;
  const int m0 = by * 128, n0 = bx * 128;

  const int tid  = threadIdx.x;
  const int lane = tid & 63;
  const int wv   = tid >> 6;
  const int quad = lane >> 4, l16 = lane & 15;
  const int wm   = wv & 1,   wn  = wv >> 1;

  const int rl   = lane >> 2;
  const int sseg = (lane & 3) ^ ((lane >> 3) & 3);     // xor-swizzled k-segment
  const u16* Ag = A + (size_t)(m0 + wv*32 + rl) * lda + sseg*8;
  const u16* Bg = B + (size_t)(n0 + wv*32 + rl) * ldb + sseg*8;

  f32x4 acc[4][4] = {};
  const int sa = quad ^ ((l16 >> 1) & 3);              // read-side slot

  auto stage = [&](int buf, int kt){
    u16* Ad = &smem[buf*4096 + (wv*32)*32];
    u16* Bd = &smem[12288 + buf*4096 + (wv*32)*32];
    #pragma unroll
    for (int h = 0; h < 2; ++h){
      __builtin_amdgcn_global_load_lds(
          (const __attribute__((address_space(1))) void*)(Ag + kt + (size_t)(16*h)*lda),
          (__attribute__((address_space(3))) void*)(Ad + h*16*32), 16, 0, 0);
      __builtin_amdgcn_global_load_lds(
          (const __attribute__((address_space(1))) void*)(Bg + kt + (size_t)(16*h)*ldb),
          (__attribute__((address_space(3))) void*)(Bd + h*16*32), 16, 0, 0);
    }
  };

  const int nit = KPd >> 5;                // 13 or 52
  stage(0, 0);
  stage(1, 32);
  int nb = 2;
  for (int it = 0; it < nit; ++it){
    if (it < nit - 1) __builtin_amdgcn_s_waitcnt(WAIT_VM4);
    else              __builtin_amdgcn_s_waitcnt(WAIT_VM0);
    __builtin_amdgcn_s_barrier();
    if (it + 2 < nit){
      stage(nb, (it + 2) << 5);
      nb = (nb == 2) ? 0 : nb + 1;
    }
    const int buf = it % 3;
    const u16* Ar = &smem[buf*4096];
    const u16* Br = &smem[12288 + buf*4096];
    frag af[4], bfr[4];
    #pragma unroll
    for (int i = 0; i < 4; ++i){
      af[i]  = *(const frag*)(&Ar[(wm*64 + i*16 + l16)*32 + sa*8]);
      bfr[i] = *(const frag*)(&Br[(wn*64 + i*16 + l16)*32 + sa*8]);
    }
    #pragma unroll
    for (int i = 0; i < 4; ++i)
      #pragma unroll
      for (int j = 0; j < 4; ++j)
        acc[i][j] = __builtin_amdgcn_mfma_f32_16x16x32_bf16(af[i], bfr[j], acc[i][j], 0, 0, 0);
  }

  __builtin_amdgcn_s_barrier();            // staging LDS now reusable

  u16* ep = &smem[wv * 4608];              // 64 rows x 72 u16
  #pragma unroll
  for (int j = 0; j < 4; ++j){
    int n = n0 + wn*64 + j*16 + l16;
    float bj = (n < Nn) ? bias[n] : 0.f;
    #pragma unroll
    for (int i = 0; i < 4; ++i){
      #pragma unroll
      for (int r = 0; r < 4; ++r){
        float v = acc[i][j][r] + bj;
        if (ACT) v = gelu_f(v);
        ep[(i*16 + quad*4 + r)*72 + j*16 + l16] = f2bf(v);
      }
    }
  }
  #pragma unroll
  for (int p = 0; p < 8; ++p){
    int row = p*8 + (lane >> 3);
    int seg = lane & 7;
    uint4 v = *(const uint4*)(&ep[row*72 + seg*8]);
    *(uint4*)(C + (size_t)(m0 + wm*64 + row)*ldc + n0 + wn*64 + seg*8) = v;
  }
}

// ---- attention for one chunk of windows; 16B vectorized staging ----
__global__ __launch_bounds__(256) void attn_kernel(const u16* __restrict__ qkv,
                                                   u16* __restrict__ o,
                                                   int g0){
  __shared__ float sq[L_ * 1200];
  __shared__ float sc[H_ * L_ * L_];
  __shared__ float att[H_ * L_ * L_];
  const int g = g0 + blockIdx.x;
  const int n = g / W_, w = g % W_;
  const int tid = threadIdx.x;

  for (int i = tid; i < L_ * 150; i += 256){
    int l = i / 150, ck = i % 150;
    uint4 v = *(const uint4*)(qkv + ((size_t)(n*T_ + w + l)) * SQKV_ + ck*8);
    unpack8(v, &sq[l*1200 + ck*8]);
  }
  __syncthreads();

  if (tid < H_ * L_ * L_){
    int h = tid / (L_*L_), rem = tid % (L_*L_), qi = rem / L_, ki = rem % L_;
    const float* qp = &sq[qi*1200 + h*DH_];
    const float* kp = &sq[ki*1200 + D_ + h*DH_];
    float s = 0.f;
    for (int dd = 0; dd < DH_; ++dd) s += qp[dd] * kp[dd];
    sc[tid] = s * 0.07071067811865475f;  // 1/sqrt(200)
  }
  __syncthreads();

  if (tid < H_ * L_){
    int base = tid * L_;
    float mx = -1e30f;
    for (int j = 0; j < L_; ++j) mx = fmaxf(mx, sc[base + j]);
    float sum = 0.f;
    for (int j = 0; j < L_; ++j){ float e = __expf(sc[base + j] - mx); att[base + j] = e; sum += e; }
    float inv = 1.f / sum;
    for (int j = 0; j < L_; ++j) att[base + j] *= inv;
  }
  __syncthreads();

  for (int i = tid; i < L_ * D_; i += 256){
    int l = i / D_, d = i % D_;
    int h = d / DH_;
    float a = 0.f;
    #pragma unroll
    for (int ki = 0; ki < L_; ++ki)
      a += att[h*(L_*L_) + l*L_ + ki] * sq[ki*1200 + 2*D_ + d];
    o[((size_t)blockIdx.x * L_ + l) * SD_ + d] = f2bf(a);
  }
}

// ---- LN1: h = LN(xs_window + y), wave-per-row (4 rows/block, no barriers) ----
__global__ __launch_bounds__(256) void ln1_kernel(const u16* __restrict__ y,
                                                  const float* __restrict__ gam,
                                                  const float* __restrict__ bet,
                                                  u16* __restrict__ out,
                                                  const u16* __restrict__ xs,
                                                  int g0){
  const int wv = threadIdx.x >> 6, lane = threadIdx.x & 63;
  const int r = blockIdx.x * 4 + wv;           // < RC_ (grid exact)
  const int g = g0 + r / L_, l = r % L_;
  const int n = g / W_, w = g % W_;
  const u16* arow = xs + ((size_t)(n*T_ + w + l)) * SD_;
  const u16* brow = y + (size_t)r * SD_;

  const bool act = lane < 50;
  float v[8];
  float s = 0.f, s2 = 0.f;
  if (act){
    float a8[8], b8[8];
    unpack8(*(const uint4*)(arow + lane*8), a8);
    unpack8(*(const uint4*)(brow + lane*8), b8);
    #pragma unroll
    for (int i = 0; i < 8; ++i){ v[i] = a8[i] + b8[i]; s += v[i]; s2 += v[i]*v[i]; }
  } else {
    #pragma unroll
    for (int i = 0; i < 8; ++i) v[i] = 0.f;
  }
  #pragma unroll
  for (int off = 32; off; off >>= 1){
    s  += __shfl_xor(s,  off);
    s2 += __shfl_xor(s2, off);
  }
  float mean = s * (1.f / D_);
  float rstd = rsqrtf(s2 * (1.f / D_) - mean*mean + 1e-5f);
  if (act){
    float4 ga = *(const float4*)(gam + lane*8);
    float4 gb = *(const float4*)(gam + lane*8 + 4);
    float4 ba = *(const float4*)(bet + lane*8);
    float4 bb = *(const float4*)(bet + lane*8 + 4);
    float gg[8] = {ga.x,ga.y,ga.z,ga.w, gb.x,gb.y,gb.z,gb.w};
    float bb8[8]= {ba.x,ba.y,ba.z,ba.w, bb.x,bb.y,bb.z,bb.w};
    u32 o4[4];
    #pragma unroll
    for (int i = 0; i < 4; ++i){
      u16 lo = f2bf((v[2*i]   - mean) * rstd * gg[2*i]   + bb8[2*i]);
      u16 hi = f2bf((v[2*i+1] - mean) * rstd * gg[2*i+1] + bb8[2*i+1]);
      o4[i] = (u32)lo | ((u32)hi << 16);
    }
    *(uint4*)(out + (size_t)r * SD_ + lane*8) = make_uint4(o4[0],o4[1],o4[2],o4[3]);
  }
}

// ---- LN2 + scatter fused: acc[t-row] += LN(h_row + y_row), wave-per-row ----
__global__ __launch_bounds__(256) void ln2_scatter_kernel(const u16* __restrict__ h,
                                                          const u16* __restrict__ y,
                                                          const float* __restrict__ gam,
                                                          const float* __restrict__ bet,
                                                          float* __restrict__ acc,
                                                          int g0){
  const int wv = threadIdx.x >> 6, lane = threadIdx.x & 63;
  const int r = blockIdx.x * 4 + wv;
  const int g = g0 + r / L_, l = r % L_;
  const int n = g / W_, w = g % W_;
  const int t = (w >> 1) + l;
  const u16* arow = h + (size_t)r * SD_;
  const u16* brow = y + (size_t)r * SD_;

  const bool act = lane < 50;
  float v[8];
  float s = 0.f, s2 = 0.f;
  if (act){
    float a8[8], b8[8];
    unpack8(*(const uint4*)(arow + lane*8), a8);
    unpack8(*(const uint4*)(brow + lane*8), b8);
    #pragma unroll
    for (int i = 0; i < 8; ++i){ v[i] = a8[i] + b8[i]; s += v[i]; s2 += v[i]*v[i]; }
  } else {
    #pragma unroll
    for (int i = 0; i < 8; ++i) v[i] = 0.f;
  }
  #pragma unroll
  for (int off = 32; off; off >>= 1){
    s  += __shfl_xor(s,  off);
    s2 += __shfl_xor(s2, off);
  }
  float mean = s * (1.f / D_);
  float rstd = rsqrtf(s2 * (1.f / D_) - mean*mean + 1e-5f);
  if (act){
    float4 ga = *(const float4*)(gam + lane*8);
    float4 gb = *(const float4*)(gam + lane*8 + 4);
    float4 ba = *(const float4*)(bet + lane*8);
    float4 bb = *(const float4*)(bet + lane*8 + 4);
    float gg[8] = {ga.x,ga.y,ga.z,ga.w, gb.x,gb.y,gb.z,gb.w};
    float bb8[8]= {ba.x,ba.y,ba.z,ba.w, bb.x,bb.y,bb.z,bb.w};
    float* dst = acc + ((size_t)(n*T_ + t)) * D_ + lane*8;
    #pragma unroll
    for (int i = 0; i < 8; ++i)
      atomicAdd(dst + i, (v[i] - mean) * rstd * gg[i] + bb8[i]);
  }
}

// ---- acc[n,t,d] -> out[n,c,t,v] fp32 ----
__global__ __launch_bounds__(256) void final_kernel(const float* __restrict__ acc,
                                                    float* __restrict__ dout){
  int idx = blockIdx.x * 256 + threadIdx.x;
  if (idx >= NT_ * D_) return;
  int d  = idx % D_;
  int nt = idx / D_;
  int t  = nt % T_;
  int n  = nt / T_;
  dout[(((size_t)(n*C_ + (d & 15)))*T_ + t)*V_ + (d >> 4)] = acc[idx];
}

extern "C" void kernel_launch(void* const* d_in, const int* in_sizes, int n_in,
                              void* d_out, int out_size, void* d_ws, size_t ws_size,
                              hipStream_t stream){
  (void)in_sizes; (void)n_in; (void)out_size; (void)ws_size;
  const float* x     = (const float*)d_in[0];
  const float* pe    = (const float*)d_in[1];
  const float* w_in  = (const float*)d_in[2];
  const float* b_in  = (const float*)d_in[3];
  const float* w_out = (const float*)d_in[4];
  const float* b_out = (const float*)d_in[5];
  const float* w1    = (const float*)d_in[6];
  const float* b1    = (const float*)d_in[7];
  const float* w2    = (const float*)d_in[8];
  const float* b2    = (const float*)d_in[9];
  const float* ln1g  = (const float*)d_in[10];
  const float* ln1b  = (const float*)d_in[11];
  const float* ln2g  = (const float*)d_in[12];
  const float* ln2b  = (const float*)d_in[13];

  char* ws = (char*)d_ws;
  u16*   w_in_b  = (u16*)(ws + WIN_OFF);
  u16*   w_out_b = (u16*)(ws + WOUT_OFF);
  u16*   w1_b    = (u16*)(ws + W1_OFF);
  u16*   w2_b    = (u16*)(ws + W2_OFF);
  u16*   xs      = (u16*)(ws + XS_OFF);
  u16*   qkv     = (u16*)(ws + QKV_OFF);
  float* acc     = (float*)(ws + ACC_OFF);
  u16*   o_c     = (u16*)(ws + OC_OFF);
  u16*   y_c     = (u16*)(ws + YC_OFF);
  u16*   h_c     = (u16*)(ws + HC_OFF);
  u16*   ffc     = (u16*)(ws + FFC_OFF);

  convw_kernel<<<(1280*KP_  + 255)/256, 256, 0, stream>>>(w_in,  w_in_b,  1280, KP_, 1200, D_);
  convw_kernel<<<( 512*KP_  + 255)/256, 256, 0, stream>>>(w_out, w_out_b,  512, KP_,  400, D_);
  convw_kernel<<<(1664*KP_  + 255)/256, 256, 0, stream>>>(w1,    w1_b,    1664, KP_, 1600, D_);
  convw_kernel<<<( 512*SFF_ + 255)/256, 256, 0, stream>>>(w2,    w2_b,     512, SFF_, 400, FF_);

  zero_kernel<<<(NT_*D_ + 255)/256, 256, 0, stream>>>(acc, NT_*D_);
  embed_kernel<<<(NT_*D_ + 255)/256, 256, 0, stream>>>(x, pe, xs);

  // qkv = xs @ w_in^T + b_in   [4800 x 1200]
  {
    int gx = SQKV_/128, gy = (NT_ + 127)/128, gy8 = (gy + 7) & ~7;
    gemm_mfma<0><<<gx*gy8, 256, 0, stream>>>(
        xs, SD_, w_in_b, KP_, b_in, qkv, SQKV_, 1200, KP_, gx, gy);
  }

  const int gyc = RCP_/128, gyc8 = (gyc + 7) & ~7;   // 110, 112

  for (int g0 = 0; g0 < NW_; g0 += CW_){
    attn_kernel<<<CW_, 256, 0, stream>>>(qkv, o_c, g0);

    gemm_mfma<0><<<(SD_/128)*gyc8, 256, 0, stream>>>(
        o_c, SD_, w_out_b, KP_, b_out, y_c, SD_, D_, KP_, SD_/128, gyc);

    ln1_kernel<<<RC_/4, 256, 0, stream>>>(y_c, ln1g, ln1b, h_c, xs, g0);

    gemm_mfma<1><<<(SFF_/128)*gyc8, 256, 0, stream>>>(
        h_c, SD_, w1_b, KP_, b1, ffc, SFF_, FF_, KP_, SFF_/128, gyc);

    gemm_mfma<0><<<(SD_/128)*gyc8, 256, 0, stream>>>(
        ffc, SFF_, w2_b, SFF_, b2, y_c, SD_, D_, FF_, SD_/128, gyc);

    ln2_scatter_kernel<<<RC_/4, 256, 0, stream>>>(h_c, y_c, ln2g, ln2b, acc, g0);
  }

  final_kernel<<<(NT_*D_ + 255)/256, 256, 0, stream>>>(acc, (float*)d_out);
}

// Round 13
// 518.921 us; speedup vs baseline: 1.7549x; 1.7549x over previous
//
#include <hip/hip_runtime.h>
#include <cstdint>
#include <cstddef>

// ---- problem constants ----
#define N_    16
#define C_    16
#define T_    300
#define V_    25
#define D_    400
#define H_    2
#define DH_   200
#define FF_   1600
#define L_    9
#define W_    291
#define NW_   (N_*W_)      // 4656
#define NT_   (N_*T_)      // 4800
#define CW_   1552         // windows per chunk -> 3 chunks
#define RC_   (CW_*L_)     // 13968 rows per chunk (= 4*3492)
#define RCP_  14080        // padded chunk rows (110*128)

#define KP_   416          // K-pad of D (mult of 32), zero-filled in weights
#define SD_   512          // row stride of D-wide intermediates
#define SQKV_ 1280         // qkv row stride / QKV N-pad
#define SFF_  1664         // ffc row stride / FFN1 N-pad

// ---- workspace layout (bytes), total 119,803,904 ----
#define WIN_OFF   0u
#define WOUT_OFF  1064960u
#define W1_OFF    1490944u
#define W2_OFF    2875392u
#define XS_OFF    4579328u
#define QKV_OFF   9560064u
#define ACC_OFF   22011904u
#define OC_OFF    29691904u
#define YC_OFF    44109824u
#define HC_OFF    58527744u
#define FFC_OFF   72945664u

// s_waitcnt immediates (gfx9): vmcnt[3:0] | expcnt<<4 | lgkmcnt<<8 | vmcnt[5:4]<<14
#define WAIT_VM4   0xF74    // vmcnt<=4, lgkm/exp don't-care
#define WAIT_VM0   0xF70    // vmcnt<=0

using u16 = unsigned short;
using u32 = unsigned int;
using frag  = __attribute__((ext_vector_type(8))) short;   // 8 bf16
using f32x4 = __attribute__((ext_vector_type(4))) float;

__device__ __forceinline__ float bf2f(u16 u){
  return __uint_as_float(((u32)u) << 16);
}
// round-half-up bf16 (differs from RNE only on exact ties; 2 VALU)
__device__ __forceinline__ u16 f2bf(float f){
  return (u16)((__float_as_uint(f) + 0x8000u) >> 16);
}
// tanh-form gelu (max dev from erf-gelu ~1e-3; invisible at bf16)
__device__ __forceinline__ float gelu_f(float v){
  float v3  = v * v * v;
  float x2  = 1.5957691216f * v + 0.0713548162726f * v3;
  float e   = __expf(x2);
  float th  = 1.f - 2.f / (e + 1.f);
  return 0.5f * v * (1.f + th);
}
__device__ __forceinline__ void unpack8(uint4 v, float* o){
  o[0] = bf2f((u16)(v.x & 0xffffu)); o[1] = bf2f((u16)(v.x >> 16));
  o[2] = bf2f((u16)(v.y & 0xffffu)); o[3] = bf2f((u16)(v.y >> 16));
  o[4] = bf2f((u16)(v.z & 0xffffu)); o[5] = bf2f((u16)(v.z >> 16));
  o[6] = bf2f((u16)(v.w & 0xffffu)); o[7] = bf2f((u16)(v.w >> 16));
}

__global__ __launch_bounds__(256) void zero_kernel(float* __restrict__ acc, int n){
  int idx = blockIdx.x * 256 + threadIdx.x;
  if (idx < n) acc[idx] = 0.f;
}

// fp32 [sN,sK] -> bf16 [dN,dK], zero-filled pad
__global__ __launch_bounds__(256) void convw_kernel(const float* __restrict__ src,
                                                    u16* __restrict__ dst,
                                                    int dN, int dK, int sN, int sK){
  int idx = blockIdx.x * 256 + threadIdx.x;
  if (idx >= dN * dK) return;
  int n = idx / dK, k = idx % dK;
  dst[idx] = (n < sN && k < sK) ? f2bf(src[(size_t)n * sK + k]) : (u16)0;
}

// ---- xs[nt, d] (stride SD_) = x[n, d&15, t, d>>4] + pe[t,d] ----
__global__ __launch_bounds__(256) void embed_kernel(const float* __restrict__ x,
                                                    const float* __restrict__ pe,
                                                    u16* __restrict__ xs){
  int idx = blockIdx.x * 256 + threadIdx.x;
  if (idx >= NT_ * D_) return;
  int d  = idx % D_;
  int nt = idx / D_;
  int t  = nt % T_;
  int n  = nt / T_;
  float val = x[(((size_t)(n*C_ + (d & 15)))*T_ + t)*V_ + (d >> 4)] + pe[t*D_ + d];
  xs[(size_t)nt * SD_ + d] = f2bf(val);
}

// ---- MFMA GEMM: shared 128x128 tile, 3-deep LDS pipeline, cooperative
//      global_load_lds staging, raw s_barrier + vmcnt(4) (never 0).
//      Epilogue via stride-72 LDS tiles -> coalesced dwordx4 stores. ----
template<int ACT>
__global__ __launch_bounds__(256) void gemm_mfma(const u16* __restrict__ A, int lda,
                                                 const u16* __restrict__ B, int ldb,
                                                 const float* __restrict__ bias,
                                                 u16* __restrict__ C, int ldc,
                                                 int Nn, int KPd,
                                                 int gx, int gy){
  __shared__ u16 smem[24576];              // 48KB
  int id = blockIdx.x;
  int c  = id & 7, t = id >> 3;
  int bx = t % gx;
  int by = (t / gx) * 8 + c;               // XCD c owns M-tile residue class
  if (by >= gy) return;
  const int m0 = by * 128, n0 = bx * 128;

  const int tid  = threadIdx.x;
  const int lane = tid & 63;
  const int wv   = tid >> 6;
  const int quad = lane >> 4, l16 = lane & 15;
  const int wm   = wv & 1,   wn  = wv >> 1;

  const int rl   = lane >> 2;
  const int sseg = (lane & 3) ^ ((lane >> 3) & 3);     // xor-swizzled k-segment
  const u16* Ag = A + (size_t)(m0 + wv*32 + rl) * lda + sseg*8;
  const u16* Bg = B + (size_t)(n0 + wv*32 + rl) * ldb + sseg*8;

  f32x4 acc[4][4] = {};
  const int sa = quad ^ ((l16 >> 1) & 3);              // read-side slot

  auto stage = [&](int buf, int kt){
    u16* Ad = &smem[buf*4096 + (wv*32)*32];
    u16* Bd = &smem[12288 + buf*4096 + (wv*32)*32];
    #pragma unroll
    for (int h = 0; h < 2; ++h){
      __builtin_amdgcn_global_load_lds(
          (const __attribute__((address_space(1))) void*)(Ag + kt + (size_t)(16*h)*lda),
          (__attribute__((address_space(3))) void*)(Ad + h*16*32), 16, 0, 0);
      __builtin_amdgcn_global_load_lds(
          (const __attribute__((address_space(1))) void*)(Bg + kt + (size_t)(16*h)*ldb),
          (__attribute__((address_space(3))) void*)(Bd + h*16*32), 16, 0, 0);
    }
  };

  const int nit = KPd >> 5;                // 13 or 52
  stage(0, 0);
  stage(1, 32);
  int nb = 2;
  for (int it = 0; it < nit; ++it){
    if (it < nit - 1) __builtin_amdgcn_s_waitcnt(WAIT_VM4);
    else              __builtin_amdgcn_s_waitcnt(WAIT_VM0);
    __builtin_amdgcn_s_barrier();
    if (it + 2 < nit){
      stage(nb, (it + 2) << 5);
      nb = (nb == 2) ? 0 : nb + 1;
    }
    const int buf = it % 3;
    const u16* Ar = &smem[buf*4096];
    const u16* Br = &smem[12288 + buf*4096];
    frag af[4], bfr[4];
    #pragma unroll
    for (int i = 0; i < 4; ++i){
      af[i]  = *(const frag*)(&Ar[(wm*64 + i*16 + l16)*32 + sa*8]);
      bfr[i] = *(const frag*)(&Br[(wn*64 + i*16 + l16)*32 + sa*8]);
    }
    #pragma unroll
    for (int i = 0; i < 4; ++i)
      #pragma unroll
      for (int j = 0; j < 4; ++j)
        acc[i][j] = __builtin_amdgcn_mfma_f32_16x16x32_bf16(af[i], bfr[j], acc[i][j], 0, 0, 0);
  }

  __builtin_amdgcn_s_barrier();            // staging LDS now reusable

  u16* ep = &smem[wv * 4608];              // 64 rows x 72 u16
  #pragma unroll
  for (int j = 0; j < 4; ++j){
    int n = n0 + wn*64 + j*16 + l16;
    float bj = (n < Nn) ? bias[n] : 0.f;
    #pragma unroll
    for (int i = 0; i < 4; ++i){
      #pragma unroll
      for (int r = 0; r < 4; ++r){
        float v = acc[i][j][r] + bj;
        if (ACT) v = gelu_f(v);
        ep[(i*16 + quad*4 + r)*72 + j*16 + l16] = f2bf(v);
      }
    }
  }
  #pragma unroll
  for (int p = 0; p < 8; ++p){
    int row = p*8 + (lane >> 3);
    int seg = lane & 7;
    uint4 v = *(const uint4*)(&ep[row*72 + seg*8]);
    *(uint4*)(C + (size_t)(m0 + wm*64 + row)*ldc + n0 + wn*64 + seg*8) = v;
  }
}

// ---- attention for one chunk of windows; 16B vectorized staging ----
__global__ __launch_bounds__(256) void attn_kernel(const u16* __restrict__ qkv,
                                                   u16* __restrict__ o,
                                                   int g0){
  __shared__ float sq[L_ * 1200];
  __shared__ float sc[H_ * L_ * L_];
  __shared__ float att[H_ * L_ * L_];
  const int g = g0 + blockIdx.x;
  const int n = g / W_, w = g % W_;
  const int tid = threadIdx.x;

  for (int i = tid; i < L_ * 150; i += 256){
    int l = i / 150, ck = i % 150;
    uint4 v = *(const uint4*)(qkv + ((size_t)(n*T_ + w + l)) * SQKV_ + ck*8);
    unpack8(v, &sq[l*1200 + ck*8]);
  }
  __syncthreads();

  if (tid < H_ * L_ * L_){
    int h = tid / (L_*L_), rem = tid % (L_*L_), qi = rem / L_, ki = rem % L_;
    const float* qp = &sq[qi*1200 + h*DH_];
    const float* kp = &sq[ki*1200 + D_ + h*DH_];
    float s = 0.f;
    for (int dd = 0; dd < DH_; ++dd) s += qp[dd] * kp[dd];
    sc[tid] = s * 0.07071067811865475f;  // 1/sqrt(200)
  }
  __syncthreads();

  if (tid < H_ * L_){
    int base = tid * L_;
    float mx = -1e30f;
    for (int j = 0; j < L_; ++j) mx = fmaxf(mx, sc[base + j]);
    float sum = 0.f;
    for (int j = 0; j < L_; ++j){ float e = __expf(sc[base + j] - mx); att[base + j] = e; sum += e; }
    float inv = 1.f / sum;
    for (int j = 0; j < L_; ++j) att[base + j] *= inv;
  }
  __syncthreads();

  for (int i = tid; i < L_ * D_; i += 256){
    int l = i / D_, d = i % D_;
    int h = d / DH_;
    float a = 0.f;
    #pragma unroll
    for (int ki = 0; ki < L_; ++ki)
      a += att[h*(L_*L_) + l*L_ + ki] * sq[ki*1200 + 2*D_ + d];
    o[((size_t)blockIdx.x * L_ + l) * SD_ + d] = f2bf(a);
  }
}

// ---- LN1: h = LN(xs_window + y), wave-per-row (4 rows/block, no barriers) ----
__global__ __launch_bounds__(256) void ln1_kernel(const u16* __restrict__ y,
                                                  const float* __restrict__ gam,
                                                  const float* __restrict__ bet,
                                                  u16* __restrict__ out,
                                                  const u16* __restrict__ xs,
                                                  int g0){
  const int wv = threadIdx.x >> 6, lane = threadIdx.x & 63;
  const int r = blockIdx.x * 4 + wv;           // < RC_ (grid exact)
  const int g = g0 + r / L_, l = r % L_;
  const int n = g / W_, w = g % W_;
  const u16* arow = xs + ((size_t)(n*T_ + w + l)) * SD_;
  const u16* brow = y + (size_t)r * SD_;

  const bool act = lane < 50;
  float v[8];
  float s = 0.f, s2 = 0.f;
  if (act){
    float a8[8], b8[8];
    unpack8(*(const uint4*)(arow + lane*8), a8);
    unpack8(*(const uint4*)(brow + lane*8), b8);
    #pragma unroll
    for (int i = 0; i < 8; ++i){ v[i] = a8[i] + b8[i]; s += v[i]; s2 += v[i]*v[i]; }
  } else {
    #pragma unroll
    for (int i = 0; i < 8; ++i) v[i] = 0.f;
  }
  #pragma unroll
  for (int off = 32; off; off >>= 1){
    s  += __shfl_xor(s,  off);
    s2 += __shfl_xor(s2, off);
  }
  float mean = s * (1.f / D_);
  float rstd = rsqrtf(s2 * (1.f / D_) - mean*mean + 1e-5f);
  if (act){
    float4 ga = *(const float4*)(gam + lane*8);
    float4 gb = *(const float4*)(gam + lane*8 + 4);
    float4 ba = *(const float4*)(bet + lane*8);
    float4 bb = *(const float4*)(bet + lane*8 + 4);
    float gg[8] = {ga.x,ga.y,ga.z,ga.w, gb.x,gb.y,gb.z,gb.w};
    float bb8[8]= {ba.x,ba.y,ba.z,ba.w, bb.x,bb.y,bb.z,bb.w};
    u32 o4[4];
    #pragma unroll
    for (int i = 0; i < 4; ++i){
      u16 lo = f2bf((v[2*i]   - mean) * rstd * gg[2*i]   + bb8[2*i]);
      u16 hi = f2bf((v[2*i+1] - mean) * rstd * gg[2*i+1] + bb8[2*i+1]);
      o4[i] = (u32)lo | ((u32)hi << 16);
    }
    *(uint4*)(out + (size_t)r * SD_ + lane*8) = make_uint4(o4[0],o4[1],o4[2],o4[3]);
  }
}

// ---- LN2 + scatter fused, COALESCED atomics: wave computes LN into LDS row
//      buffer; then all 256 threads emit consecutive-lane-consecutive-d
//      atomicAdds (wave = 4 full cachelines, no write amplification). ----
__global__ __launch_bounds__(256) void ln2_scatter_kernel(const u16* __restrict__ h,
                                                          const u16* __restrict__ y,
                                                          const float* __restrict__ gam,
                                                          const float* __restrict__ bet,
                                                          float* __restrict__ acc,
                                                          int g0){
  __shared__ float buf[4][400];
  const int wv = threadIdx.x >> 6, lane = threadIdx.x & 63;
  const int tid = threadIdx.x;
  const int r0 = blockIdx.x * 4;
  {
    const int r = r0 + wv;
    const u16* arow = h + (size_t)r * SD_;
    const u16* brow = y + (size_t)r * SD_;
    const bool act = lane < 50;
    float v[8];
    float s = 0.f, s2 = 0.f;
    if (act){
      float a8[8], b8[8];
      unpack8(*(const uint4*)(arow + lane*8), a8);
      unpack8(*(const uint4*)(brow + lane*8), b8);
      #pragma unroll
      for (int i = 0; i < 8; ++i){ v[i] = a8[i] + b8[i]; s += v[i]; s2 += v[i]*v[i]; }
    } else {
      #pragma unroll
      for (int i = 0; i < 8; ++i) v[i] = 0.f;
    }
    #pragma unroll
    for (int off = 32; off; off >>= 1){
      s  += __shfl_xor(s,  off);
      s2 += __shfl_xor(s2, off);
    }
    float mean = s * (1.f / D_);
    float rstd = rsqrtf(s2 * (1.f / D_) - mean*mean + 1e-5f);
    if (act){
      float4 ga = *(const float4*)(gam + lane*8);
      float4 gb = *(const float4*)(gam + lane*8 + 4);
      float4 ba = *(const float4*)(bet + lane*8);
      float4 bb = *(const float4*)(bet + lane*8 + 4);
      float gg[8] = {ga.x,ga.y,ga.z,ga.w, gb.x,gb.y,gb.z,gb.w};
      float bb8[8]= {ba.x,ba.y,ba.z,ba.w, bb.x,bb.y,bb.z,bb.w};
      #pragma unroll
      for (int i = 0; i < 8; ++i)
        buf[wv][lane*8 + i] = (v[i] - mean) * rstd * gg[i] + bb8[i];
    }
  }
  __syncthreads();
  // coalesced atomic phase: rows r0..r0+3, d = tid, tid+256
  #pragma unroll
  for (int rr = 0; rr < 4; ++rr){
    int r = r0 + rr;
    int g = g0 + r / L_, l = r % L_;
    int n = g / W_, w = g % W_;
    size_t base = ((size_t)(n*T_ + (w >> 1) + l)) * D_;
    atomicAdd(acc + base + tid, buf[rr][tid]);
    if (tid + 256 < D_) atomicAdd(acc + base + tid + 256, buf[rr][tid + 256]);
  }
}

// ---- acc[n,t,d] -> out[n,c,t,v] fp32 ----
__global__ __launch_bounds__(256) void final_kernel(const float* __restrict__ acc,
                                                    float* __restrict__ dout){
  int idx = blockIdx.x * 256 + threadIdx.x;
  if (idx >= NT_ * D_) return;
  int d  = idx % D_;
  int nt = idx / D_;
  int t  = nt % T_;
  int n  = nt / T_;
  dout[(((size_t)(n*C_ + (d & 15)))*T_ + t)*V_ + (d >> 4)] = acc[idx];
}

extern "C" void kernel_launch(void* const* d_in, const int* in_sizes, int n_in,
                              void* d_out, int out_size, void* d_ws, size_t ws_size,
                              hipStream_t stream){
  (void)in_sizes; (void)n_in; (void)out_size; (void)ws_size;
  const float* x     = (const float*)d_in[0];
  const float* pe    = (const float*)d_in[1];
  const float* w_in  = (const float*)d_in[2];
  const float* b_in  = (const float*)d_in[3];
  const float* w_out = (const float*)d_in[4];
  const float* b_out = (const float*)d_in[5];
  const float* w1    = (const float*)d_in[6];
  const float* b1    = (const float*)d_in[7];
  const float* w2    = (const float*)d_in[8];
  const float* b2    = (const float*)d_in[9];
  const float* ln1g  = (const float*)d_in[10];
  const float* ln1b  = (const float*)d_in[11];
  const float* ln2g  = (const float*)d_in[12];
  const float* ln2b  = (const float*)d_in[13];

  char* ws = (char*)d_ws;
  u16*   w_in_b  = (u16*)(ws + WIN_OFF);
  u16*   w_out_b = (u16*)(ws + WOUT_OFF);
  u16*   w1_b    = (u16*)(ws + W1_OFF);
  u16*   w2_b    = (u16*)(ws + W2_OFF);
  u16*   xs      = (u16*)(ws + XS_OFF);
  u16*   qkv     = (u16*)(ws + QKV_OFF);
  float* acc     = (float*)(ws + ACC_OFF);
  u16*   o_c     = (u16*)(ws + OC_OFF);
  u16*   y_c     = (u16*)(ws + YC_OFF);
  u16*   h_c     = (u16*)(ws + HC_OFF);
  u16*   ffc     = (u16*)(ws + FFC_OFF);

  convw_kernel<<<(1280*KP_  + 255)/256, 256, 0, stream>>>(w_in,  w_in_b,  1280, KP_, 1200, D_);
  convw_kernel<<<( 512*KP_  + 255)/256, 256, 0, stream>>>(w_out, w_out_b,  512, KP_,  400, D_);
  convw_kernel<<<(1664*KP_  + 255)/256, 256, 0, stream>>>(w1,    w1_b,    1664, KP_, 1600, D_);
  convw_kernel<<<( 512*SFF_ + 255)/256, 256, 0, stream>>>(w2,    w2_b,     512, SFF_, 400, FF_);

  zero_kernel<<<(NT_*D_ + 255)/256, 256, 0, stream>>>(acc, NT_*D_);
  embed_kernel<<<(NT_*D_ + 255)/256, 256, 0, stream>>>(x, pe, xs);

  // qkv = xs @ w_in^T + b_in   [4800 x 1200]
  {
    int gx = SQKV_/128, gy = (NT_ + 127)/128, gy8 = (gy + 7) & ~7;
    gemm_mfma<0><<<gx*gy8, 256, 0, stream>>>(
        xs, SD_, w_in_b, KP_, b_in, qkv, SQKV_, 1200, KP_, gx, gy);
  }

  const int gyc = RCP_/128, gyc8 = (gyc + 7) & ~7;   // 110, 112

  for (int g0 = 0; g0 < NW_; g0 += CW_){
    attn_kernel<<<CW_, 256, 0, stream>>>(qkv, o_c, g0);

    gemm_mfma<0><<<(SD_/128)*gyc8, 256, 0, stream>>>(
        o_c, SD_, w_out_b, KP_, b_out, y_c, SD_, D_, KP_, SD_/128, gyc);

    ln1_kernel<<<RC_/4, 256, 0, stream>>>(y_c, ln1g, ln1b, h_c, xs, g0);

    gemm_mfma<1><<<(SFF_/128)*gyc8, 256, 0, stream>>>(
        h_c, SD_, w1_b, KP_, b1, ffc, SFF_, FF_, KP_, SFF_/128, gyc);

    gemm_mfma<0><<<(SD_/128)*gyc8, 256, 0, stream>>>(
        ffc, SFF_, w2_b, SFF_, b2, y_c, SD_, D_, FF_, SD_/128, gyc);

    ln2_scatter_kernel<<<RC_/4, 256, 0, stream>>>(h_c, y_c, ln2g, ln2b, acc, g0);
  }

  final_kernel<<<(NT_*D_ + 255)/256, 256, 0, stream>>>(acc, (float*)d_out);
}

// Round 14
// 461.770 us; speedup vs baseline: 1.9721x; 1.1238x over previous
//
#include <hip/hip_runtime.h>
#include <cstdint>
#include <cstddef>

// ---- problem constants ----
#define N_    16
#define C_    16
#define T_    300
#define V_    25
#define D_    400
#define H_    2
#define DH_   200
#define FF_   1600
#define L_    9
#define W_    291
#define NW_   (N_*W_)      // 4656
#define NT_   (N_*T_)      // 4800

#define KP_   416          // K-pad of D for staging (mult of 32); B zero-padded
#define SD_   400          // tight row stride of D-wide intermediates (800B, 16B-aligned)
#define SQKV_ 1200         // tight qkv row stride
#define SFF_  1600         // tight ffc row stride (= FFN2 K, exact)

// fixed workspace head (bytes)
#define WIN_OFF   0u           // w_in_b  [1280][416]
#define WOUT_OFF  1064960u     // w_out_b [512][416]
#define W1_OFF    1490944u     // w1_b    [1664][416]
#define W2_OFF    2875392u     // w2_b    [512][1600]
#define XS_OFF    4513792u     // xs      [4864][400]
#define QKV_OFF   8404992u     // qkv     [4864][1200]
#define ACC_OFF   20078592u    // acc fp32[4800][400]
#define HEAD_END  27758592u

// s_waitcnt immediates (gfx9): vmcnt[3:0] | expcnt<<4 | lgkmcnt<<8 | vmcnt[5:4]<<14
#define WAIT_VM4   0xF74
#define WAIT_VM0   0xF70

using u16 = unsigned short;
using u32 = unsigned int;
using frag  = __attribute__((ext_vector_type(8))) short;   // 8 bf16
using f32x4 = __attribute__((ext_vector_type(4))) float;

__device__ __forceinline__ float bf2f(u16 u){
  return __uint_as_float(((u32)u) << 16);
}
__device__ __forceinline__ u16 f2bf(float f){
  return (u16)((__float_as_uint(f) + 0x8000u) >> 16);   // round-half-up
}
// tanh-form gelu (max dev from erf-gelu ~1e-3; invisible at bf16)
__device__ __forceinline__ float gelu_f(float v){
  float v3  = v * v * v;
  float x2  = 1.5957691216f * v + 0.0713548162726f * v3;
  float e   = __expf(x2);
  float th  = 1.f - 2.f / (e + 1.f);
  return 0.5f * v * (1.f + th);
}
__device__ __forceinline__ void unpack8(uint4 v, float* o){
  o[0] = bf2f((u16)(v.x & 0xffffu)); o[1] = bf2f((u16)(v.x >> 16));
  o[2] = bf2f((u16)(v.y & 0xffffu)); o[3] = bf2f((u16)(v.y >> 16));
  o[4] = bf2f((u16)(v.z & 0xffffu)); o[5] = bf2f((u16)(v.z >> 16));
  o[6] = bf2f((u16)(v.w & 0xffffu)); o[7] = bf2f((u16)(v.w >> 16));
}

__global__ __launch_bounds__(256) void zero_kernel(float* __restrict__ acc, int n){
  int idx = blockIdx.x * 256 + threadIdx.x;
  if (idx < n) acc[idx] = 0.f;
}

// fp32 [sN,sK] -> bf16 [dN,dK], zero-filled pad
__global__ __launch_bounds__(256) void convw_kernel(const float* __restrict__ src,
                                                    u16* __restrict__ dst,
                                                    int dN, int dK, int sN, int sK){
  int idx = blockIdx.x * 256 + threadIdx.x;
  if (idx >= dN * dK) return;
  int n = idx / dK, k = idx % dK;
  dst[idx] = (n < sN && k < sK) ? f2bf(src[(size_t)n * sK + k]) : (u16)0;
}

// ---- xs[nt*400 + d] = x[n, d&15, t, d>>4] + pe[t,d] (dense) ----
__global__ __launch_bounds__(256) void embed_kernel(const float* __restrict__ x,
                                                    const float* __restrict__ pe,
                                                    u16* __restrict__ xs){
  int idx = blockIdx.x * 256 + threadIdx.x;
  if (idx >= NT_ * D_) return;
  int d  = idx % D_;
  int nt = idx / D_;
  int t  = nt % T_;
  int n  = nt / T_;
  float val = x[(((size_t)(n*C_ + (d & 15)))*T_ + t)*V_ + (d >> 4)] + pe[t*D_ + d];
  xs[idx] = f2bf(val);
}

// ---- MFMA GEMM: shared 128x128 tile, 3-deep LDS pipeline, cooperative
//      global_load_lds staging, raw s_barrier + vmcnt(4) (never 0).
//      Epilogue via stride-72 LDS tiles -> dwordx4 stores, seg-guarded by Nn.
//      A K-spill reads (KPd>lda) hit next-row data x zero-padded B = 0.  ----
template<int ACT>
__global__ __launch_bounds__(256) void gemm_mfma(const u16* __restrict__ A, int lda,
                                                 const u16* __restrict__ B, int ldb,
                                                 const float* __restrict__ bias,
                                                 u16* __restrict__ C, int ldc,
                                                 int Nn, int KPd,
                                                 int gx, int gy){
  __shared__ u16 smem[24576];              // 48KB
  int id = blockIdx.x;
  int c  = id & 7, t = id >> 3;
  int bx = t % gx;
  int by = (t / gx) * 8 + c;               // XCD c owns M-tile residue class
  if (by >= gy) return;
  const int m0 = by * 128, n0 = bx * 128;

  const int tid  = threadIdx.x;
  const int lane = tid & 63;
  const int wv   = tid >> 6;
  const int quad = lane >> 4, l16 = lane & 15;
  const int wm   = wv & 1,   wn  = wv >> 1;

  const int rl   = lane >> 2;
  const int sseg = (lane & 3) ^ ((lane >> 3) & 3);     // xor-swizzled k-segment
  const u16* Ag = A + (size_t)(m0 + wv*32 + rl) * lda + sseg*8;
  const u16* Bg = B + (size_t)(n0 + wv*32 + rl) * ldb + sseg*8;

  f32x4 acc[4][4] = {};
  const int sa = quad ^ ((l16 >> 1) & 3);              // read-side slot

  auto stage = [&](int buf, int kt){
    u16* Ad = &smem[buf*4096 + (wv*32)*32];
    u16* Bd = &smem[12288 + buf*4096 + (wv*32)*32];
    #pragma unroll
    for (int h = 0; h < 2; ++h){
      __builtin_amdgcn_global_load_lds(
          (const __attribute__((address_space(1))) void*)(Ag + kt + (size_t)(16*h)*lda),
          (__attribute__((address_space(3))) void*)(Ad + h*16*32), 16, 0, 0);
      __builtin_amdgcn_global_load_lds(
          (const __attribute__((address_space(1))) void*)(Bg + kt + (size_t)(16*h)*ldb),
          (__attribute__((address_space(3))) void*)(Bd + h*16*32), 16, 0, 0);
    }
  };

  const int nit = KPd >> 5;                // 13 or 50
  stage(0, 0);
  stage(1, 32);
  int nb = 2;
  for (int it = 0; it < nit; ++it){
    if (it < nit - 1) __builtin_amdgcn_s_waitcnt(WAIT_VM4);
    else              __builtin_amdgcn_s_waitcnt(WAIT_VM0);
    __builtin_amdgcn_s_barrier();
    if (it + 2 < nit){
      stage(nb, (it + 2) << 5);
      nb = (nb == 2) ? 0 : nb + 1;
    }
    const int buf = it % 3;
    const u16* Ar = &smem[buf*4096];
    const u16* Br = &smem[12288 + buf*4096];
    frag af[4], bfr[4];
    #pragma unroll
    for (int i = 0; i < 4; ++i){
      af[i]  = *(const frag*)(&Ar[(wm*64 + i*16 + l16)*32 + sa*8]);
      bfr[i] = *(const frag*)(&Br[(wn*64 + i*16 + l16)*32 + sa*8]);
    }
    #pragma unroll
    for (int i = 0; i < 4; ++i)
      #pragma unroll
      for (int j = 0; j < 4; ++j)
        acc[i][j] = __builtin_amdgcn_mfma_f32_16x16x32_bf16(af[i], bfr[j], acc[i][j], 0, 0, 0);
  }

  __builtin_amdgcn_s_barrier();            // staging LDS now reusable

  u16* ep = &smem[wv * 4608];              // 64 rows x 72 u16
  #pragma unroll
  for (int j = 0; j < 4; ++j){
    int n = n0 + wn*64 + j*16 + l16;
    float bj = (n < Nn) ? bias[n] : 0.f;
    #pragma unroll
    for (int i = 0; i < 4; ++i){
      #pragma unroll
      for (int r = 0; r < 4; ++r){
        float v = acc[i][j][r] + bj;
        if (ACT) v = gelu_f(v);
        ep[(i*16 + quad*4 + r)*72 + j*16 + l16] = f2bf(v);
      }
    }
  }
  #pragma unroll
  for (int p = 0; p < 8; ++p){
    int row = p*8 + (lane >> 3);
    int seg = lane & 7;
    int nc  = n0 + wn*64 + seg*8;
    if (nc < Nn){                           // Nn multiple of 8 -> seg-exact
      uint4 v = *(const uint4*)(&ep[row*72 + seg*8]);
      *(uint4*)(C + (size_t)(m0 + wm*64 + row)*ldc + nc) = v;
    }
  }
}

// ---- attention for one chunk of windows; 16B vectorized staging ----
__global__ __launch_bounds__(256) void attn_kernel(const u16* __restrict__ qkv,
                                                   u16* __restrict__ o,
                                                   int g0){
  __shared__ float sq[L_ * 1200];
  __shared__ float sc[H_ * L_ * L_];
  __shared__ float att[H_ * L_ * L_];
  const int g = g0 + blockIdx.x;
  const int n = g / W_, w = g % W_;
  const int tid = threadIdx.x;

  for (int i = tid; i < L_ * 150; i += 256){
    int l = i / 150, ck = i % 150;
    uint4 v = *(const uint4*)(qkv + ((size_t)(n*T_ + w + l)) * SQKV_ + ck*8);
    unpack8(v, &sq[l*1200 + ck*8]);
  }
  __syncthreads();

  if (tid < H_ * L_ * L_){
    int h = tid / (L_*L_), rem = tid % (L_*L_), qi = rem / L_, ki = rem % L_;
    const float* qp = &sq[qi*1200 + h*DH_];
    const float* kp = &sq[ki*1200 + D_ + h*DH_];
    float s = 0.f;
    for (int dd = 0; dd < DH_; ++dd) s += qp[dd] * kp[dd];
    sc[tid] = s * 0.07071067811865475f;  // 1/sqrt(200)
  }
  __syncthreads();

  if (tid < H_ * L_){
    int base = tid * L_;
    float mx = -1e30f;
    for (int j = 0; j < L_; ++j) mx = fmaxf(mx, sc[base + j]);
    float sum = 0.f;
    for (int j = 0; j < L_; ++j){ float e = __expf(sc[base + j] - mx); att[base + j] = e; sum += e; }
    float inv = 1.f / sum;
    for (int j = 0; j < L_; ++j) att[base + j] *= inv;
  }
  __syncthreads();

  for (int i = tid; i < L_ * D_; i += 256){
    int l = i / D_, d = i % D_;
    int h = d / DH_;
    float a = 0.f;
    #pragma unroll
    for (int ki = 0; ki < L_; ++ki)
      a += att[h*(L_*L_) + l*L_ + ki] * sq[ki*1200 + 2*D_ + d];
    o[((size_t)blockIdx.x * L_ + l) * SD_ + d] = f2bf(a);
  }
}

// ---- LN1: h = LN(xs_window + y), wave-per-row (4 rows/block, no barriers) ----
__global__ __launch_bounds__(256) void ln1_kernel(const u16* __restrict__ y,
                                                  const float* __restrict__ gam,
                                                  const float* __restrict__ bet,
                                                  u16* __restrict__ out,
                                                  const u16* __restrict__ xs,
                                                  int g0){
  const int wv = threadIdx.x >> 6, lane = threadIdx.x & 63;
  const int r = blockIdx.x * 4 + wv;
  const int g = g0 + r / L_, l = r % L_;
  const int n = g / W_, w = g % W_;
  const u16* arow = xs + ((size_t)(n*T_ + w + l)) * SD_;
  const u16* brow = y + (size_t)r * SD_;

  const bool act = lane < 50;
  float v[8];
  float s = 0.f, s2 = 0.f;
  if (act){
    float a8[8], b8[8];
    unpack8(*(const uint4*)(arow + lane*8), a8);
    unpack8(*(const uint4*)(brow + lane*8), b8);
    #pragma unroll
    for (int i = 0; i < 8; ++i){ v[i] = a8[i] + b8[i]; s += v[i]; s2 += v[i]*v[i]; }
  } else {
    #pragma unroll
    for (int i = 0; i < 8; ++i) v[i] = 0.f;
  }
  #pragma unroll
  for (int off = 32; off; off >>= 1){
    s  += __shfl_xor(s,  off);
    s2 += __shfl_xor(s2, off);
  }
  float mean = s * (1.f / D_);
  float rstd = rsqrtf(s2 * (1.f / D_) - mean*mean + 1e-5f);
  if (act){
    float4 ga = *(const float4*)(gam + lane*8);
    float4 gb = *(const float4*)(gam + lane*8 + 4);
    float4 ba = *(const float4*)(bet + lane*8);
    float4 bb = *(const float4*)(bet + lane*8 + 4);
    float gg[8] = {ga.x,ga.y,ga.z,ga.w, gb.x,gb.y,gb.z,gb.w};
    float bb8[8]= {ba.x,ba.y,ba.z,ba.w, bb.x,bb.y,bb.z,bb.w};
    u32 o4[4];
    #pragma unroll
    for (int i = 0; i < 4; ++i){
      u16 lo = f2bf((v[2*i]   - mean) * rstd * gg[2*i]   + bb8[2*i]);
      u16 hi = f2bf((v[2*i+1] - mean) * rstd * gg[2*i+1] + bb8[2*i+1]);
      o4[i] = (u32)lo | ((u32)hi << 16);
    }
    *(uint4*)(out + (size_t)r * SD_ + lane*8) = make_uint4(o4[0],o4[1],o4[2],o4[3]);
  }
}

// ---- LN2 + scatter fused, coalesced atomics via LDS row buffer ----
__global__ __launch_bounds__(256) void ln2_scatter_kernel(const u16* __restrict__ h,
                                                          const u16* __restrict__ y,
                                                          const float* __restrict__ gam,
                                                          const float* __restrict__ bet,
                                                          float* __restrict__ acc,
                                                          int g0){
  __shared__ float buf[4][400];
  const int wv = threadIdx.x >> 6, lane = threadIdx.x & 63;
  const int tid = threadIdx.x;
  const int r0 = blockIdx.x * 4;
  {
    const int r = r0 + wv;
    const u16* arow = h + (size_t)r * SD_;
    const u16* brow = y + (size_t)r * SD_;
    const bool act = lane < 50;
    float v[8];
    float s = 0.f, s2 = 0.f;
    if (act){
      float a8[8], b8[8];
      unpack8(*(const uint4*)(arow + lane*8), a8);
      unpack8(*(const uint4*)(brow + lane*8), b8);
      #pragma unroll
      for (int i = 0; i < 8; ++i){ v[i] = a8[i] + b8[i]; s += v[i]; s2 += v[i]*v[i]; }
    } else {
      #pragma unroll
      for (int i = 0; i < 8; ++i) v[i] = 0.f;
    }
    #pragma unroll
    for (int off = 32; off; off >>= 1){
      s  += __shfl_xor(s,  off);
      s2 += __shfl_xor(s2, off);
    }
    float mean = s * (1.f / D_);
    float rstd = rsqrtf(s2 * (1.f / D_) - mean*mean + 1e-5f);
    if (act){
      float4 ga = *(const float4*)(gam + lane*8);
      float4 gb = *(const float4*)(gam + lane*8 + 4);
      float4 ba = *(const float4*)(bet + lane*8);
      float4 bb = *(const float4*)(bet + lane*8 + 4);
      float gg[8] = {ga.x,ga.y,ga.z,ga.w, gb.x,gb.y,gb.z,gb.w};
      float bb8[8]= {ba.x,ba.y,ba.z,ba.w, bb.x,bb.y,bb.z,bb.w};
      #pragma unroll
      for (int i = 0; i < 8; ++i)
        buf[wv][lane*8 + i] = (v[i] - mean) * rstd * gg[i] + bb8[i];
    }
  }
  __syncthreads();
  #pragma unroll
  for (int rr = 0; rr < 4; ++rr){
    int r = r0 + rr;
    int g = g0 + r / L_, l = r % L_;
    int n = g / W_, w = g % W_;
    size_t base = ((size_t)(n*T_ + (w >> 1) + l)) * D_;
    atomicAdd(acc + base + tid, buf[rr][tid]);
    if (tid + 256 < D_) atomicAdd(acc + base + tid + 256, buf[rr][tid + 256]);
  }
}

// ---- acc[n,t,d] -> out[n,c,t,v] fp32 ----
__global__ __launch_bounds__(256) void final_kernel(const float* __restrict__ acc,
                                                    float* __restrict__ dout){
  int idx = blockIdx.x * 256 + threadIdx.x;
  if (idx >= NT_ * D_) return;
  int d  = idx % D_;
  int nt = idx / D_;
  int t  = nt % T_;
  int n  = nt / T_;
  dout[(((size_t)(n*C_ + (d & 15)))*T_ + t)*V_ + (d >> 4)] = acc[idx];
}

extern "C" void kernel_launch(void* const* d_in, const int* in_sizes, int n_in,
                              void* d_out, int out_size, void* d_ws, size_t ws_size,
                              hipStream_t stream){
  (void)in_sizes; (void)n_in; (void)out_size;
  const float* x     = (const float*)d_in[0];
  const float* pe    = (const float*)d_in[1];
  const float* w_in  = (const float*)d_in[2];
  const float* b_in  = (const float*)d_in[3];
  const float* w_out = (const float*)d_in[4];
  const float* b_out = (const float*)d_in[5];
  const float* w1    = (const float*)d_in[6];
  const float* b1    = (const float*)d_in[7];
  const float* w2    = (const float*)d_in[8];
  const float* b2    = (const float*)d_in[9];
  const float* ln1g  = (const float*)d_in[10];
  const float* ln1b  = (const float*)d_in[11];
  const float* ln2g  = (const float*)d_in[12];
  const float* ln2b  = (const float*)d_in[13];

  // ws_size-adaptive chunk count (deterministic per run -> graph-safe)
  int nch = 3;
  {
    size_t need1 = (size_t)HEAD_END + (size_t)41984 * 5600;   // 1 chunk
    size_t need2 = (size_t)HEAD_END + (size_t)20992 * 5600;   // 2 chunks
    if (ws_size >= need1 + (1u<<20)) nch = 1;
    else if (ws_size >= need2 + (1u<<20)) nch = 2;
  }
  const int CW  = NW_ / nch;          // 4656 / 2328 / 1552  (all mult of 4)
  const int RC  = CW * L_;            // rows per chunk
  const int RCP = ((RC + 127) / 128) * 128;

  char* ws = (char*)d_ws;
  u16*   w_in_b  = (u16*)(ws + WIN_OFF);
  u16*   w_out_b = (u16*)(ws + WOUT_OFF);
  u16*   w1_b    = (u16*)(ws + W1_OFF);
  u16*   w2_b    = (u16*)(ws + W2_OFF);
  u16*   xs      = (u16*)(ws + XS_OFF);
  u16*   qkv     = (u16*)(ws + QKV_OFF);
  float* acc     = (float*)(ws + ACC_OFF);
  u16*   o_c     = (u16*)(ws + HEAD_END);
  u16*   y_c     = o_c + (size_t)RCP * SD_;
  u16*   h_c     = y_c + (size_t)RCP * SD_;
  u16*   ffc     = h_c + (size_t)RCP * SD_;

  convw_kernel<<<(1280*KP_  + 255)/256, 256, 0, stream>>>(w_in,  w_in_b,  1280, KP_, 1200, D_);
  convw_kernel<<<( 512*KP_  + 255)/256, 256, 0, stream>>>(w_out, w_out_b,  512, KP_,  400, D_);
  convw_kernel<<<(1664*KP_  + 255)/256, 256, 0, stream>>>(w1,    w1_b,    1664, KP_, 1600, D_);
  convw_kernel<<<( 512*SFF_ + 255)/256, 256, 0, stream>>>(w2,    w2_b,     512, SFF_, 400, FF_);

  zero_kernel<<<(NT_*D_ + 255)/256, 256, 0, stream>>>(acc, NT_*D_);
  embed_kernel<<<(NT_*D_ + 255)/256, 256, 0, stream>>>(x, pe, xs);

  // qkv = xs @ w_in^T + b_in   [4800 x 1200]
  {
    int gx = 10, gy = (NT_ + 127)/128, gy8 = (gy + 7) & ~7;
    gemm_mfma<0><<<gx*gy8, 256, 0, stream>>>(
        xs, SD_, w_in_b, KP_, b_in, qkv, SQKV_, 1200, KP_, gx, gy);
  }

  const int gyc = RCP/128, gyc8 = (gyc + 7) & ~7;

  for (int g0 = 0; g0 < NW_; g0 += CW){
    attn_kernel<<<CW, 256, 0, stream>>>(qkv, o_c, g0);

    gemm_mfma<0><<<4*gyc8, 256, 0, stream>>>(
        o_c, SD_, w_out_b, KP_, b_out, y_c, SD_, D_, KP_, 4, gyc);

    ln1_kernel<<<RC/4, 256, 0, stream>>>(y_c, ln1g, ln1b, h_c, xs, g0);

    gemm_mfma<1><<<13*gyc8, 256, 0, stream>>>(
        h_c, SD_, w1_b, KP_, b1, ffc, SFF_, FF_, KP_, 13, gyc);

    gemm_mfma<0><<<4*gyc8, 256, 0, stream>>>(
        ffc, SFF_, w2_b, SFF_, b2, y_c, SD_, D_, SFF_, 4, gyc);

    ln2_scatter_kernel<<<RC/4, 256, 0, stream>>>(h_c, y_c, ln2g, ln2b, acc, g0);
  }

  final_kernel<<<(NT_*D_ + 255)/256, 256, 0, stream>>>(acc, (float*)d_out);
}

// Round 15
// 441.432 us; speedup vs baseline: 2.0630x; 1.0461x over previous
//
#include <hip/hip_runtime.h>
#include <cstdint>
#include <cstddef>

// ---- problem constants ----
#define N_    16
#define C_    16
#define T_    300
#define V_    25
#define D_    400
#define H_    2
#define DH_   200
#define FF_   1600
#define L_    9
#define W_    291
#define NW_   (N_*W_)      // 4656
#define NT_   (N_*T_)      // 4800

#define KP_   416          // K-pad of D for staging (mult of 32); B zero-padded
#define SD_   400          // tight row stride of D-wide intermediates
#define SQKV_ 1200         // tight qkv row stride
#define SFF_  1600         // tight ffc row stride

// fixed workspace head (bytes)
#define WIN_OFF   0u           // w_in_b  [1280][416]
#define WOUT_OFF  1064960u     // w_out_b [512][416]
#define W1_OFF    1490944u     // w1_b    [1664][416]
#define W2_OFF    2875392u     // w2_b    [512][1600]
#define XS_OFF    4513792u     // xs      [4864][400]
#define QKV_OFF   8404992u     // qkv     [4864][1200]
#define ACC_OFF   20078592u    // acc fp32[4800][400]
#define HEAD_END  27758592u

// s_waitcnt immediates (gfx9)
#define WAIT_VM4   0xF74
#define WAIT_VM0   0xF70

using u16 = unsigned short;
using u32 = unsigned int;
using frag  = __attribute__((ext_vector_type(8))) short;   // 8 bf16
using f32x4 = __attribute__((ext_vector_type(4))) float;

__device__ __forceinline__ float bf2f(u16 u){
  return __uint_as_float(((u32)u) << 16);
}
__device__ __forceinline__ u16 f2bf(float f){
  return (u16)((__float_as_uint(f) + 0x8000u) >> 16);   // round-half-up
}
// gelu: tanh-form with Pade(3,2) tanh, clamped (1 transcendental: v_rcp).
// tanh(u) ~ u(27+u^2)/(27+9u^2), exact +-1 crossing at |u|=3 -> clamp.
// max per-element dev ~0.02 (u in 1.5..3); invisible after FFN2 sum @ bf16.
__device__ __forceinline__ float gelu_f(float v){
  float v2  = v * v;
  float u   = v * (0.7978845608f + 0.03567740814f * v2);   // 0.79788*(v+0.044715v^3)
  float u2  = u * u;
  float num = u * (27.f + u2);
  float den = 27.f + 9.f * u2;
  float th  = num * __builtin_amdgcn_rcpf(den);
  th = fminf(fmaxf(th, -1.f), 1.f);
  return 0.5f * v * (1.f + th);
}
__device__ __forceinline__ void unpack8(uint4 v, float* o){
  o[0] = bf2f((u16)(v.x & 0xffffu)); o[1] = bf2f((u16)(v.x >> 16));
  o[2] = bf2f((u16)(v.y & 0xffffu)); o[3] = bf2f((u16)(v.y >> 16));
  o[4] = bf2f((u16)(v.z & 0xffffu)); o[5] = bf2f((u16)(v.z >> 16));
  o[6] = bf2f((u16)(v.w & 0xffffu)); o[7] = bf2f((u16)(v.w >> 16));
}

__device__ __forceinline__ void convw_body(const float* src, u16* dst,
                                           int dN, int dK, int sN, int sK, int idx){
  if (idx >= dN * dK) return;
  int n = idx / dK, k = idx % dK;
  dst[idx] = (n < sN && k < sK) ? f2bf(src[(size_t)n * sK + k]) : (u16)0;
}

// ---- mega-prep: zero acc | embed | 4x weight conversions, one launch ----
// block ranges: [0,7500) zero, [7500,15000) embed, [15000,17080) w_in,
// [17080,17912) w_out, [17912,20616) w1, [20616,23816) w2
#define PREP_GRID 23816
__global__ __launch_bounds__(256) void prep_kernel(const float* __restrict__ x,
                                                   const float* __restrict__ pe,
                                                   const float* __restrict__ w_in,
                                                   const float* __restrict__ w_out,
                                                   const float* __restrict__ w1,
                                                   const float* __restrict__ w2,
                                                   u16* __restrict__ xs,
                                                   u16* __restrict__ w_in_b,
                                                   u16* __restrict__ w_out_b,
                                                   u16* __restrict__ w1_b,
                                                   u16* __restrict__ w2_b,
                                                   float* __restrict__ acc){
  int b = blockIdx.x;
  int tid = threadIdx.x;
  if (b < 7500){
    int idx = b * 256 + tid;
    if (idx < NT_ * D_) acc[idx] = 0.f;
  } else if (b < 15000){
    int idx = (b - 7500) * 256 + tid;
    if (idx < NT_ * D_){
      int d  = idx % D_;
      int nt = idx / D_;
      int t  = nt % T_;
      int n  = nt / T_;
      float val = x[(((size_t)(n*C_ + (d & 15)))*T_ + t)*V_ + (d >> 4)] + pe[t*D_ + d];
      xs[idx] = f2bf(val);
    }
  } else if (b < 17080){
    convw_body(w_in,  w_in_b,  1280, KP_, 1200, D_,  (b - 15000) * 256 + tid);
  } else if (b < 17912){
    convw_body(w_out, w_out_b,  512, KP_,  400, D_,  (b - 17080) * 256 + tid);
  } else if (b < 20616){
    convw_body(w1,    w1_b,   1664, KP_, 1600, D_,  (b - 17912) * 256 + tid);
  } else {
    convw_body(w2,    w2_b,    512, SFF_, 400, FF_, (b - 20616) * 256 + tid);
  }
}

// ---- MFMA GEMM: shared 128x128 tile, 3-deep LDS pipeline, cooperative
//      global_load_lds staging, raw s_barrier + vmcnt(4) (never 0).
//      Epilogue via stride-72 LDS tiles -> dwordx4 stores, seg-guarded. ----
template<int ACT>
__global__ __launch_bounds__(256) void gemm_mfma(const u16* __restrict__ A, int lda,
                                                 const u16* __restrict__ B, int ldb,
                                                 const float* __restrict__ bias,
                                                 u16* __restrict__ C, int ldc,
                                                 int Nn, int KPd,
                                                 int gx, int gy){
  __shared__ u16 smem[24576];              // 48KB
  int id = blockIdx.x;
  int c  = id & 7, t = id >> 3;
  int bx = t % gx;
  int by = (t / gx) * 8 + c;               // XCD c owns M-tile residue class
  if (by >= gy) return;
  const int m0 = by * 128, n0 = bx * 128;

  const int tid  = threadIdx.x;
  const int lane = tid & 63;
  const int wv   = tid >> 6;
  const int quad = lane >> 4, l16 = lane & 15;
  const int wm   = wv & 1,   wn  = wv >> 1;

  const int rl   = lane >> 2;
  const int sseg = (lane & 3) ^ ((lane >> 3) & 3);     // xor-swizzled k-segment
  const u16* Ag = A + (size_t)(m0 + wv*32 + rl) * lda + sseg*8;
  const u16* Bg = B + (size_t)(n0 + wv*32 + rl) * ldb + sseg*8;

  f32x4 acc[4][4] = {};
  const int sa = quad ^ ((l16 >> 1) & 3);              // read-side slot

  auto stage = [&](int buf, int kt){
    u16* Ad = &smem[buf*4096 + (wv*32)*32];
    u16* Bd = &smem[12288 + buf*4096 + (wv*32)*32];
    #pragma unroll
    for (int h = 0; h < 2; ++h){
      __builtin_amdgcn_global_load_lds(
          (const __attribute__((address_space(1))) void*)(Ag + kt + (size_t)(16*h)*lda),
          (__attribute__((address_space(3))) void*)(Ad + h*16*32), 16, 0, 0);
      __builtin_amdgcn_global_load_lds(
          (const __attribute__((address_space(1))) void*)(Bg + kt + (size_t)(16*h)*ldb),
          (__attribute__((address_space(3))) void*)(Bd + h*16*32), 16, 0, 0);
    }
  };

  const int nit = KPd >> 5;                // 13 or 50
  stage(0, 0);
  stage(1, 32);
  int nb = 2;
  for (int it = 0; it < nit; ++it){
    if (it < nit - 1) __builtin_amdgcn_s_waitcnt(WAIT_VM4);
    else              __builtin_amdgcn_s_waitcnt(WAIT_VM0);
    __builtin_amdgcn_s_barrier();
    if (it + 2 < nit){
      stage(nb, (it + 2) << 5);
      nb = (nb == 2) ? 0 : nb + 1;
    }
    const int buf = it % 3;
    const u16* Ar = &smem[buf*4096];
    const u16* Br = &smem[12288 + buf*4096];
    frag af[4], bfr[4];
    #pragma unroll
    for (int i = 0; i < 4; ++i){
      af[i]  = *(const frag*)(&Ar[(wm*64 + i*16 + l16)*32 + sa*8]);
      bfr[i] = *(const frag*)(&Br[(wn*64 + i*16 + l16)*32 + sa*8]);
    }
    #pragma unroll
    for (int i = 0; i < 4; ++i)
      #pragma unroll
      for (int j = 0; j < 4; ++j)
        acc[i][j] = __builtin_amdgcn_mfma_f32_16x16x32_bf16(af[i], bfr[j], acc[i][j], 0, 0, 0);
  }

  __builtin_amdgcn_s_barrier();            // staging LDS now reusable

  u16* ep = &smem[wv * 4608];              // 64 rows x 72 u16
  #pragma unroll
  for (int j = 0; j < 4; ++j){
    int n = n0 + wn*64 + j*16 + l16;
    float bj = (n < Nn) ? bias[n] : 0.f;
    #pragma unroll
    for (int i = 0; i < 4; ++i){
      #pragma unroll
      for (int r = 0; r < 4; ++r){
        float v = acc[i][j][r] + bj;
        if (ACT) v = gelu_f(v);
        ep[(i*16 + quad*4 + r)*72 + j*16 + l16] = f2bf(v);
      }
    }
  }
  #pragma unroll
  for (int p = 0; p < 8; ++p){
    int row = p*8 + (lane >> 3);
    int seg = lane & 7;
    int nc  = n0 + wn*64 + seg*8;
    if (nc < Nn){                           // Nn multiple of 8 -> seg-exact
      uint4 v = *(const uint4*)(&ep[row*72 + seg*8]);
      *(uint4*)(C + (size_t)(m0 + wm*64 + row)*ldc + nc) = v;
    }
  }
}

// ---- attention for one chunk of windows; 16B vectorized staging ----
__global__ __launch_bounds__(256) void attn_kernel(const u16* __restrict__ qkv,
                                                   u16* __restrict__ o,
                                                   int g0){
  __shared__ float sq[L_ * 1200];
  __shared__ float sc[H_ * L_ * L_];
  __shared__ float att[H_ * L_ * L_];
  const int g = g0 + blockIdx.x;
  const int n = g / W_, w = g % W_;
  const int tid = threadIdx.x;

  for (int i = tid; i < L_ * 150; i += 256){
    int l = i / 150, ck = i % 150;
    uint4 v = *(const uint4*)(qkv + ((size_t)(n*T_ + w + l)) * SQKV_ + ck*8);
    unpack8(v, &sq[l*1200 + ck*8]);
  }
  __syncthreads();

  if (tid < H_ * L_ * L_){
    int h = tid / (L_*L_), rem = tid % (L_*L_), qi = rem / L_, ki = rem % L_;
    const float* qp = &sq[qi*1200 + h*DH_];
    const float* kp = &sq[ki*1200 + D_ + h*DH_];
    float s = 0.f;
    for (int dd = 0; dd < DH_; ++dd) s += qp[dd] * kp[dd];
    sc[tid] = s * 0.07071067811865475f;  // 1/sqrt(200)
  }
  __syncthreads();

  if (tid < H_ * L_){
    int base = tid * L_;
    float mx = -1e30f;
    for (int j = 0; j < L_; ++j) mx = fmaxf(mx, sc[base + j]);
    float sum = 0.f;
    for (int j = 0; j < L_; ++j){ float e = __expf(sc[base + j] - mx); att[base + j] = e; sum += e; }
    float inv = 1.f / sum;
    for (int j = 0; j < L_; ++j) att[base + j] *= inv;
  }
  __syncthreads();

  for (int i = tid; i < L_ * D_; i += 256){
    int l = i / D_, d = i % D_;
    int h = d / DH_;
    float a = 0.f;
    #pragma unroll
    for (int ki = 0; ki < L_; ++ki)
      a += att[h*(L_*L_) + l*L_ + ki] * sq[ki*1200 + 2*D_ + d];
    o[((size_t)blockIdx.x * L_ + l) * SD_ + d] = f2bf(a);
  }
}

// ---- LN1: h = LN(xs_window + y), wave-per-row ----
__global__ __launch_bounds__(256) void ln1_kernel(const u16* __restrict__ y,
                                                  const float* __restrict__ gam,
                                                  const float* __restrict__ bet,
                                                  u16* __restrict__ out,
                                                  const u16* __restrict__ xs,
                                                  int g0){
  const int wv = threadIdx.x >> 6, lane = threadIdx.x & 63;
  const int r = blockIdx.x * 4 + wv;
  const int g = g0 + r / L_, l = r % L_;
  const int n = g / W_, w = g % W_;
  const u16* arow = xs + ((size_t)(n*T_ + w + l)) * SD_;
  const u16* brow = y + (size_t)r * SD_;

  const bool act = lane < 50;
  float v[8];
  float s = 0.f, s2 = 0.f;
  if (act){
    float a8[8], b8[8];
    unpack8(*(const uint4*)(arow + lane*8), a8);
    unpack8(*(const uint4*)(brow + lane*8), b8);
    #pragma unroll
    for (int i = 0; i < 8; ++i){ v[i] = a8[i] + b8[i]; s += v[i]; s2 += v[i]*v[i]; }
  } else {
    #pragma unroll
    for (int i = 0; i < 8; ++i) v[i] = 0.f;
  }
  #pragma unroll
  for (int off = 32; off; off >>= 1){
    s  += __shfl_xor(s,  off);
    s2 += __shfl_xor(s2, off);
  }
  float mean = s * (1.f / D_);
  float rstd = rsqrtf(s2 * (1.f / D_) - mean*mean + 1e-5f);
  if (act){
    float4 ga = *(const float4*)(gam + lane*8);
    float4 gb = *(const float4*)(gam + lane*8 + 4);
    float4 ba = *(const float4*)(bet + lane*8);
    float4 bb = *(const float4*)(bet + lane*8 + 4);
    float gg[8] = {ga.x,ga.y,ga.z,ga.w, gb.x,gb.y,gb.z,gb.w};
    float bb8[8]= {ba.x,ba.y,ba.z,ba.w, bb.x,bb.y,bb.z,bb.w};
    u32 o4[4];
    #pragma unroll
    for (int i = 0; i < 4; ++i){
      u16 lo = f2bf((v[2*i]   - mean) * rstd * gg[2*i]   + bb8[2*i]);
      u16 hi = f2bf((v[2*i+1] - mean) * rstd * gg[2*i+1] + bb8[2*i+1]);
      o4[i] = (u32)lo | ((u32)hi << 16);
    }
    *(uint4*)(out + (size_t)r * SD_ + lane*8) = make_uint4(o4[0],o4[1],o4[2],o4[3]);
  }
}

// ---- LN2 + scatter fused, coalesced atomics via LDS row buffer ----
__global__ __launch_bounds__(256) void ln2_scatter_kernel(const u16* __restrict__ h,
                                                          const u16* __restrict__ y,
                                                          const float* __restrict__ gam,
                                                          const float* __restrict__ bet,
                                                          float* __restrict__ acc,
                                                          int g0){
  __shared__ float buf[4][400];
  const int wv = threadIdx.x >> 6, lane = threadIdx.x & 63;
  const int tid = threadIdx.x;
  const int r0 = blockIdx.x * 4;
  {
    const int r = r0 + wv;
    const u16* arow = h + (size_t)r * SD_;
    const u16* brow = y + (size_t)r * SD_;
    const bool act = lane < 50;
    float v[8];
    float s = 0.f, s2 = 0.f;
    if (act){
      float a8[8], b8[8];
      unpack8(*(const uint4*)(arow + lane*8), a8);
      unpack8(*(const uint4*)(brow + lane*8), b8);
      #pragma unroll
      for (int i = 0; i < 8; ++i){ v[i] = a8[i] + b8[i]; s += v[i]; s2 += v[i]*v[i]; }
    } else {
      #pragma unroll
      for (int i = 0; i < 8; ++i) v[i] = 0.f;
    }
    #pragma unroll
    for (int off = 32; off; off >>= 1){
      s  += __shfl_xor(s,  off);
      s2 += __shfl_xor(s2, off);
    }
    float mean = s * (1.f / D_);
    float rstd = rsqrtf(s2 * (1.f / D_) - mean*mean + 1e-5f);
    if (act){
      float4 ga = *(const float4*)(gam + lane*8);
      float4 gb = *(const float4*)(gam + lane*8 + 4);
      float4 ba = *(const float4*)(bet + lane*8);
      float4 bb = *(const float4*)(bet + lane*8 + 4);
      float gg[8] = {ga.x,ga.y,ga.z,ga.w, gb.x,gb.y,gb.z,gb.w};
      float bb8[8]= {ba.x,ba.y,ba.z,ba.w, bb.x,bb.y,bb.z,bb.w};
      #pragma unroll
      for (int i = 0; i < 8; ++i)
        buf[wv][lane*8 + i] = (v[i] - mean) * rstd * gg[i] + bb8[i];
    }
  }
  __syncthreads();
  #pragma unroll
  for (int rr = 0; rr < 4; ++rr){
    int r = r0 + rr;
    int g = g0 + r / L_, l = r % L_;
    int n = g / W_, w = g % W_;
    size_t base = ((size_t)(n*T_ + (w >> 1) + l)) * D_;
    atomicAdd(acc + base + tid, buf[rr][tid]);
    if (tid + 256 < D_) atomicAdd(acc + base + tid + 256, buf[rr][tid + 256]);
  }
}

// ---- acc[n,t,d] -> out[n,c,t,v] fp32 ----
__global__ __launch_bounds__(256) void final_kernel(const float* __restrict__ acc,
                                                    float* __restrict__ dout){
  int idx = blockIdx.x * 256 + threadIdx.x;
  if (idx >= NT_ * D_) return;
  int d  = idx % D_;
  int nt = idx / D_;
  int t  = nt % T_;
  int n  = nt / T_;
  dout[(((size_t)(n*C_ + (d & 15)))*T_ + t)*V_ + (d >> 4)] = acc[idx];
}

extern "C" void kernel_launch(void* const* d_in, const int* in_sizes, int n_in,
                              void* d_out, int out_size, void* d_ws, size_t ws_size,
                              hipStream_t stream){
  (void)in_sizes; (void)n_in; (void)out_size;
  const float* x     = (const float*)d_in[0];
  const float* pe    = (const float*)d_in[1];
  const float* w_in  = (const float*)d_in[2];
  const float* b_in  = (const float*)d_in[3];
  const float* w_out = (const float*)d_in[4];
  const float* b_out = (const float*)d_in[5];
  const float* w1    = (const float*)d_in[6];
  const float* b1    = (const float*)d_in[7];
  const float* w2    = (const float*)d_in[8];
  const float* b2    = (const float*)d_in[9];
  const float* ln1g  = (const float*)d_in[10];
  const float* ln1b  = (const float*)d_in[11];
  const float* ln2g  = (const float*)d_in[12];
  const float* ln2b  = (const float*)d_in[13];

  // ws_size-adaptive chunk count (deterministic -> graph-safe)
  int nch = 3;
  {
    size_t need1 = (size_t)HEAD_END + (size_t)41984 * 5600;   // 1 chunk
    size_t need2 = (size_t)HEAD_END + (size_t)20992 * 5600;   // 2 chunks
    if (ws_size >= need1 + (1u<<20)) nch = 1;
    else if (ws_size >= need2 + (1u<<20)) nch = 2;
  }
  const int CW  = NW_ / nch;
  const int RC  = CW * L_;
  const int RCP = ((RC + 127) / 128) * 128;

  char* ws = (char*)d_ws;
  u16*   w_in_b  = (u16*)(ws + WIN_OFF);
  u16*   w_out_b = (u16*)(ws + WOUT_OFF);
  u16*   w1_b    = (u16*)(ws + W1_OFF);
  u16*   w2_b    = (u16*)(ws + W2_OFF);
  u16*   xs      = (u16*)(ws + XS_OFF);
  u16*   qkv     = (u16*)(ws + QKV_OFF);
  float* acc     = (float*)(ws + ACC_OFF);
  u16*   o_c     = (u16*)(ws + HEAD_END);
  u16*   y_c     = o_c + (size_t)RCP * SD_;
  u16*   h_c     = y_c + (size_t)RCP * SD_;
  u16*   ffc     = h_c + (size_t)RCP * SD_;

  // one launch: zero acc + embed + all 4 weight conversions
  prep_kernel<<<PREP_GRID, 256, 0, stream>>>(x, pe, w_in, w_out, w1, w2,
                                             xs, w_in_b, w_out_b, w1_b, w2_b, acc);

  // qkv = xs @ w_in^T + b_in   [4800 x 1200]
  {
    int gx = 10, gy = (NT_ + 127)/128, gy8 = (gy + 7) & ~7;
    gemm_mfma<0><<<gx*gy8, 256, 0, stream>>>(
        xs, SD_, w_in_b, KP_, b_in, qkv, SQKV_, 1200, KP_, gx, gy);
  }

  const int gyc = RCP/128, gyc8 = (gyc + 7) & ~7;

  for (int g0 = 0; g0 < NW_; g0 += CW){
    attn_kernel<<<CW, 256, 0, stream>>>(qkv, o_c, g0);

    gemm_mfma<0><<<4*gyc8, 256, 0, stream>>>(
        o_c, SD_, w_out_b, KP_, b_out, y_c, SD_, D_, KP_, 4, gyc);

    ln1_kernel<<<RC/4, 256, 0, stream>>>(y_c, ln1g, ln1b, h_c, xs, g0);

    gemm_mfma<1><<<13*gyc8, 256, 0, stream>>>(
        h_c, SD_, w1_b, KP_, b1, ffc, SFF_, FF_, KP_, 13, gyc);

    gemm_mfma<0><<<4*gyc8, 256, 0, stream>>>(
        ffc, SFF_, w2_b, SFF_, b2, y_c, SD_, D_, SFF_, 4, gyc);

    ln2_scatter_kernel<<<RC/4, 256, 0, stream>>>(h_c, y_c, ln2g, ln2b, acc, g0);
  }

  final_kernel<<<(NT_*D_ + 255)/256, 256, 0, stream>>>(acc, (float*)d_out);
}